// Round 3
// baseline (742.096 us; speedup 1.0000x reference)
//
#include <hip/hip_runtime.h>
#include <stdint.h>

typedef __bf16 bf16_t;
typedef __bf16 bf16x8 __attribute__((ext_vector_type(8)));
typedef __bf16 bf16x4 __attribute__((ext_vector_type(4)));
typedef float  f32x4  __attribute__((ext_vector_type(4)));

static constexpr int S  = 4096;
static constexpr int D  = 2048;
static constexpr int H  = 16;
static constexpr int DH = 128;

__device__ __forceinline__ bf16x8 ld8c(const bf16_t* p) { return *(const bf16x8*)p; }
// f32 source: load 2x float4, round to bf16x8 (device buffers are float32!)
__device__ __forceinline__ bf16x8 ld8c(const float* p) {
  const f32x4 a = *(const f32x4*)p;
  const f32x4 b = *(const f32x4*)(p + 4);
  bf16x8 r;
  r[0] = (bf16_t)a[0]; r[1] = (bf16_t)a[1]; r[2] = (bf16_t)a[2]; r[3] = (bf16_t)a[3];
  r[4] = (bf16_t)b[0]; r[5] = (bf16_t)b[1]; r[6] = (bf16_t)b[2]; r[7] = (bf16_t)b[3];
  return r;
}

// ---------------------------------------------------------------------------
// NT GEMM: C[M,N] = A[M,K] * W[N,K]^T  (f32/bf16 in -> bf16 MFMA, fp32 acc)
// 128x128 tile, BK=32, 256 threads, LDS row stride 40 (2-way alias = free).
// ---------------------------------------------------------------------------
template <typename TA, typename TW, typename TC>
__device__ __forceinline__ void gemm_body(const TA* __restrict__ A,
                                          const TW* __restrict__ W,
                                          TC* __restrict__ C) {
  constexpr int K  = D;
  constexpr int BK = 32;
  constexpr int LD = 40;
  __shared__ __align__(16) bf16_t Ash[128 * LD];
  __shared__ __align__(16) bf16_t Bsh[128 * LD];
  const int tid = threadIdx.x;
  const int w = tid >> 6, lane = tid & 63;
  const int c = lane & 15, g = lane >> 4;
  const int wm = w >> 1, wn = w & 1;
  const int rowBase = blockIdx.y * 128;
  const int colBase = blockIdx.x * 128;

  f32x4 acc[4][4] = {};

  for (int k0 = 0; k0 < K; k0 += BK) {
    __syncthreads();  // prior tile's LDS reads done
    #pragma unroll
    for (int r = 0; r < 2; ++r) {
      const int cid = r * 256 + tid;           // 8-elem chunk id, [0,512)
      const int row = cid >> 2, q = cid & 3;
      const bf16x8 av = ld8c(A + (size_t)(rowBase + row) * K + k0 + q * 8);
      const bf16x8 wv = ld8c(W + (size_t)(colBase + row) * K + k0 + q * 8);
      *(bf16x8*)(Ash + row * LD + q * 8) = av;
      *(bf16x8*)(Bsh + row * LD + q * 8) = wv;
    }
    __syncthreads();

    bf16x8 af[4], bf[4];
    #pragma unroll
    for (int i = 0; i < 4; ++i) af[i] = *(const bf16x8*)(Ash + (wm * 64 + i * 16 + c) * LD + g * 8);
    #pragma unroll
    for (int j = 0; j < 4; ++j) bf[j] = *(const bf16x8*)(Bsh + (wn * 64 + j * 16 + c) * LD + g * 8);
    #pragma unroll
    for (int i = 0; i < 4; ++i)
      #pragma unroll
      for (int j = 0; j < 4; ++j)
        acc[i][j] = __builtin_amdgcn_mfma_f32_16x16x32_bf16(af[i], bf[j], acc[i][j], 0, 0, 0);
  }

  // epilogue: C/D layout col=lane&15, row=(lane>>4)*4+reg  (m89/m91 verified)
  #pragma unroll
  for (int i = 0; i < 4; ++i)
    #pragma unroll
    for (int j = 0; j < 4; ++j)
      #pragma unroll
      for (int r = 0; r < 4; ++r) {
        const int row = rowBase + wm * 64 + i * 16 + g * 4 + r;
        const int col = colBase + wn * 64 + j * 16 + c;
        C[(size_t)row * D + col] = (TC)acc[i][j][r];
      }
}

__global__ __launch_bounds__(256) void qkv_gemm(
    const float* __restrict__ X,
    const float* __restrict__ Wq, const float* __restrict__ Wk,
    const float* __restrict__ Wv,
    bf16_t* __restrict__ Qo, bf16_t* __restrict__ Ko, bf16_t* __restrict__ Vo) {
  const float* W = (blockIdx.z == 0) ? Wq : (blockIdx.z == 1 ? Wk : Wv);
  bf16_t*      C = (blockIdx.z == 0) ? Qo : (blockIdx.z == 1 ? Ko : Vo);
  gemm_body<float, float, bf16_t>(X, W, C);
}

__global__ __launch_bounds__(256) void out_gemm(
    const bf16_t* __restrict__ A, const float* __restrict__ W,
    float* __restrict__ C) {
  gemm_body<bf16_t, float, float>(A, W, C);
}

// ---------------------------------------------------------------------------
// Causal flash attention (bf16 Q/K/V from workspace). Block = (q-tile 128) x
// head; 4 waves, 32 q-rows each; K-tile = 64. LDS rows stride 40.
//   Ksh[d-chunk(4)][kn(64)][40]   B-frag for QK^T
//   Vt [k-chunk(2)][d(128)][40]   B-frag for P*V (transposed)
//   Psh[wave(4)][k-chunk(2)][qr(32)][40]  A-frag for P*V
// ---------------------------------------------------------------------------
__global__ __launch_bounds__(256) void attn_kernel(
    const bf16_t* __restrict__ Q, const bf16_t* __restrict__ Kb,
    const bf16_t* __restrict__ Vb, bf16_t* __restrict__ O,
    const int* __restrict__ causal_p) {
  constexpr int KT = 64;
  constexpr int LDK = 40;
  __shared__ __align__(16) bf16_t Ksh[4 * 64 * LDK];        // 20 KB
  __shared__ __align__(16) bf16_t Vt[2 * 128 * LDK];        // 20 KB
  __shared__ __align__(16) bf16_t Psh[4 * 2 * 32 * LDK];    // 20 KB

  const int qt = blockIdx.x, h = blockIdx.y;
  const int tid = threadIdx.x, w = tid >> 6, lane = tid & 63;
  const int c = lane & 15, g = lane >> 4;
  const int qbase = qt * 128 + w * 32;
  const int causal = causal_p[0];
  const float sm = 0.08838834764831845f;  // 1/sqrt(128)

  // Q fragments in registers (A layout: m=lane&15, k=(lane>>4)*8+j; m120)
  bf16x8 qf[2][4];
  #pragma unroll
  for (int i = 0; i < 2; ++i)
    #pragma unroll
    for (int kf = 0; kf < 4; ++kf)
      qf[i][kf] = ld8c(Q + (size_t)(qbase + i * 16 + c) * D + h * DH + kf * 32 + g * 8);

  f32x4 o_acc[2][8] = {};
  float m_st[2][4], l_st[2][4];
  #pragma unroll
  for (int i = 0; i < 2; ++i)
    #pragma unroll
    for (int r = 0; r < 4; ++r) { m_st[i][r] = -1e30f; l_st[i][r] = 0.f; }

  const int ktiles = causal ? (2 * qt + 2) : (S / KT);

  for (int kt = 0; kt < ktiles; ++kt) {
    __syncthreads();  // everyone done with prev tile's Ksh/Vt

    // --- stage K tile: 1024 8-elem chunks, 4 per thread ---
    #pragma unroll
    for (int r = 0; r < 4; ++r) {
      const int cid = r * 256 + tid;
      const int kn = cid >> 4, d0 = (cid & 15) * 8;
      const bf16x8 kv = ld8c(Kb + (size_t)(kt * KT + kn) * D + h * DH + d0);
      *(bf16x8*)(Ksh + (d0 >> 5) * (64 * LDK) + kn * LDK + (d0 & 31)) = kv;
    }
    // --- stage V transposed: thread does 4(kn) x 8(d) sub-block ---
    {
      const int kn0 = (tid & 15) * 4, d0 = (tid >> 4) * 8;
      const int chunk = kn0 >> 5, knin = kn0 & 31;
      bf16x8 vv[4];
      #pragma unroll
      for (int rr = 0; rr < 4; ++rr)
        vv[rr] = ld8c(Vb + (size_t)(kt * KT + kn0 + rr) * D + h * DH + d0);
      #pragma unroll
      for (int jj = 0; jj < 8; ++jj) {
        bf16x4 t;
        t[0] = vv[0][jj]; t[1] = vv[1][jj]; t[2] = vv[2][jj]; t[3] = vv[3][jj];
        *(bf16x4*)(Vt + chunk * (128 * LDK) + (d0 + jj) * LDK + knin) = t;
      }
    }
    __syncthreads();

    // --- S = Q K^T : per wave 32x64, fp32 acc ---
    f32x4 s[2][4] = {};
    #pragma unroll
    for (int nf = 0; nf < 4; ++nf) {
      bf16x8 kk[4];
      #pragma unroll
      for (int kf = 0; kf < 4; ++kf)
        kk[kf] = *(const bf16x8*)(Ksh + kf * (64 * LDK) + (nf * 16 + c) * LDK + g * 8);
      #pragma unroll
      for (int i = 0; i < 2; ++i)
        #pragma unroll
        for (int kf = 0; kf < 4; ++kf)
          s[i][nf] = __builtin_amdgcn_mfma_f32_16x16x32_bf16(qf[i][kf], kk[kf], s[i][nf], 0, 0, 0);
    }

    // --- causal mask ---
    if (causal && (kt * KT + KT - 1 > qbase)) {
      #pragma unroll
      for (int i = 0; i < 2; ++i)
        #pragma unroll
        for (int nf = 0; nf < 4; ++nf)
          #pragma unroll
          for (int r = 0; r < 4; ++r) {
            const int kc = kt * KT + nf * 16 + c;
            const int qr = qbase + i * 16 + g * 4 + r;
            if (kc > qr) s[i][nf][r] = -1e30f;
          }
    }

    // --- online softmax (rows live in 16-lane groups) + P -> LDS ---
    #pragma unroll
    for (int i = 0; i < 2; ++i)
      #pragma unroll
      for (int r = 0; r < 4; ++r) {
        float mx = fmaxf(fmaxf(s[i][0][r], s[i][1][r]), fmaxf(s[i][2][r], s[i][3][r]));
        #pragma unroll
        for (int d = 1; d < 16; d <<= 1) mx = fmaxf(mx, __shfl_xor(mx, d, 64));
        const float mnew = fmaxf(m_st[i][r], mx);
        const float alpha = __expf((m_st[i][r] - mnew) * sm);
        m_st[i][r] = mnew;
        float rs = 0.f;
        const int qr = i * 16 + g * 4 + r;
        #pragma unroll
        for (int nf = 0; nf < 4; ++nf) {
          const float p = __expf((s[i][nf][r] - mnew) * sm);
          rs += p;
          Psh[w * (2 * 32 * LDK) + (nf >> 1) * (32 * LDK) + qr * LDK + (nf & 1) * 16 + c] = (bf16_t)p;
        }
        #pragma unroll
        for (int d = 1; d < 16; d <<= 1) rs += __shfl_xor(rs, d, 64);
        l_st[i][r] = l_st[i][r] * alpha + rs;
        #pragma unroll
        for (int nf = 0; nf < 8; ++nf) o_acc[i][nf][r] *= alpha;
      }

    // --- O += P V  (per-wave Psh region; same-wave LDS ops are ordered) ---
    #pragma unroll
    for (int kf2 = 0; kf2 < 2; ++kf2) {
      bf16x8 pf[2];
      #pragma unroll
      for (int i = 0; i < 2; ++i)
        pf[i] = *(const bf16x8*)(Psh + w * (2 * 32 * LDK) + kf2 * (32 * LDK) + (i * 16 + c) * LDK + g * 8);
      #pragma unroll
      for (int nf = 0; nf < 8; ++nf) {
        const bf16x8 vf = *(const bf16x8*)(Vt + kf2 * (128 * LDK) + (nf * 16 + c) * LDK + g * 8);
        #pragma unroll
        for (int i = 0; i < 2; ++i)
          o_acc[i][nf] = __builtin_amdgcn_mfma_f32_16x16x32_bf16(pf[i], vf, o_acc[i][nf], 0, 0, 0);
      }
    }
  }

  // --- normalize and write O (bf16 workspace) ---
  #pragma unroll
  for (int i = 0; i < 2; ++i)
    #pragma unroll
    for (int r = 0; r < 4; ++r) {
      const float inv = 1.0f / l_st[i][r];
      const int row = qbase + i * 16 + g * 4 + r;
      #pragma unroll
      for (int nf = 0; nf < 8; ++nf)
        O[(size_t)row * D + h * DH + nf * 16 + c] = (bf16_t)(o_acc[i][nf][r] * inv);
    }
}

// ---------------------------------------------------------------------------
extern "C" void kernel_launch(void* const* d_in, const int* in_sizes, int n_in,
                              void* d_out, int out_size, void* d_ws, size_t ws_size,
                              hipStream_t stream) {
  const float* x  = (const float*)d_in[0];
  const float* wq = (const float*)d_in[1];
  const float* wk = (const float*)d_in[2];
  const float* wv = (const float*)d_in[3];
  const float* wo = (const float*)d_in[4];
  const int* causal = (const int*)d_in[5];
  float* out = (float*)d_out;

  bf16_t* Qb = (bf16_t*)d_ws;            // bf16 intermediates, 16 MB each
  bf16_t* Kb = Qb + (size_t)S * D;
  bf16_t* Vb = Kb + (size_t)S * D;
  bf16_t* Ob = Vb + (size_t)S * D;

  dim3 blk(256);
  qkv_gemm<<<dim3(D / 128, S / 128, 3), blk, 0, stream>>>(x, wq, wk, wv, Qb, Kb, Vb);
  attn_kernel<<<dim3(S / 128, H), blk, 0, stream>>>(Qb, Kb, Vb, Ob, causal);
  out_gemm<<<dim3(D / 128, S / 128), blk, 0, stream>>>(Ob, wo, out);
}

// Round 4
// 539.233 us; speedup vs baseline: 1.3762x; 1.3762x over previous
//
#include <hip/hip_runtime.h>
#include <stdint.h>

typedef __bf16 bf16_t;
typedef __bf16 bf16x8 __attribute__((ext_vector_type(8)));
typedef __bf16 bf16x4 __attribute__((ext_vector_type(4)));
typedef float  f32x4  __attribute__((ext_vector_type(4)));

static constexpr int S  = 4096;
static constexpr int D  = 2048;
static constexpr int H  = 16;
static constexpr int DH = 128;

__device__ __forceinline__ bf16x8 ld8(const bf16_t* p) { return *(const bf16x8*)p; }
__device__ __forceinline__ bf16x8 ld8c(const bf16_t* p) { return *(const bf16x8*)p; }
// f32 source: load 2x float4, round to bf16x8 (fallback path)
__device__ __forceinline__ bf16x8 ld8c(const float* p) {
  const f32x4 a = *(const f32x4*)p;
  const f32x4 b = *(const f32x4*)(p + 4);
  bf16x8 r;
  r[0] = (bf16_t)a[0]; r[1] = (bf16_t)a[1]; r[2] = (bf16_t)a[2]; r[3] = (bf16_t)a[3];
  r[4] = (bf16_t)b[0]; r[5] = (bf16_t)b[1]; r[6] = (bf16_t)b[2]; r[7] = (bf16_t)b[3];
  return r;
}

// async global->LDS, 16B/lane; LDS dest = wave-uniform base + lane*16 (m97/m104)
__device__ __forceinline__ void async_ld16(const bf16_t* g, bf16_t* lds) {
  __builtin_amdgcn_global_load_lds(
      (const __attribute__((address_space(1))) uint32_t*)g,
      (__attribute__((address_space(3))) uint32_t*)lds, 16, 0, 0);
}

// ---------------------------------------------------------------------------
// f32 -> bf16 convert: 6 slices of 4,194,304 elems (x = slices 0,1; weights 2-5)
// ---------------------------------------------------------------------------
__global__ __launch_bounds__(256) void cvt_kernel(
    const float* __restrict__ x,  const float* __restrict__ wq,
    const float* __restrict__ wk, const float* __restrict__ wv,
    const float* __restrict__ wo,
    bf16_t* __restrict__ xb,  bf16_t* __restrict__ wqb,
    bf16_t* __restrict__ wkb, bf16_t* __restrict__ wvb,
    bf16_t* __restrict__ wob) {
  const int z = blockIdx.z;
  const float* src; bf16_t* dst; size_t off = 0;
  if      (z == 0) { src = x;  dst = xb;  off = 0; }
  else if (z == 1) { src = x;  dst = xb;  off = 4194304; }
  else if (z == 2) { src = wq; dst = wqb; }
  else if (z == 3) { src = wk; dst = wkb; }
  else if (z == 4) { src = wv; dst = wvb; }
  else             { src = wo; dst = wob; }
  const size_t i = off + ((size_t)blockIdx.x * 256 + threadIdx.x) * 8;
  *(bf16x8*)(dst + i) = ld8c(src + i);
}

// ---------------------------------------------------------------------------
// bf16 NT GEMM with async global->LDS staging (m97 structure).
// C[M,N] = A[M,K] * W[N,K]^T ; 128x128 tile, BK=32, 256 threads.
// ---------------------------------------------------------------------------
template <typename TC>
__device__ __forceinline__ void gemm_async(const bf16_t* __restrict__ A,
                                           const bf16_t* __restrict__ W,
                                           TC* __restrict__ C) {
  constexpr int K  = D;
  constexpr int BK = 32;
  __shared__ __align__(16) bf16_t Ash[128 * BK];
  __shared__ __align__(16) bf16_t Bsh[128 * BK];
  const int tid = threadIdx.x;
  const int w = tid >> 6, lane = tid & 63;
  const int c = lane & 15, g = lane >> 4;
  const int wm = w >> 1, wn = w & 1;
  const int rowBase = blockIdx.y * 128;
  const int colBase = blockIdx.x * 128;

  f32x4 acc[4][4] = {};

  for (int k0 = 0; k0 < K; k0 += BK) {
    __syncthreads();
    #pragma unroll
    for (int r = 0; r < 2; ++r) {
      const int cid = r * 256 + tid;          // 8-elem chunk id; == LDS slot order
      const int row = cid >> 2, q = cid & 3;
      async_ld16(A + (size_t)(rowBase + row) * K + k0 + q * 8,
                 Ash + r * 2048 + w * 512);
      async_ld16(W + (size_t)(colBase + row) * K + k0 + q * 8,
                 Bsh + r * 2048 + w * 512);
    }
    __syncthreads();  // compiler emits vmcnt(0) before barrier

    bf16x8 af[4], bf[4];
    #pragma unroll
    for (int i = 0; i < 4; ++i) af[i] = ld8(Ash + (wm * 64 + i * 16 + c) * BK + g * 8);
    #pragma unroll
    for (int j = 0; j < 4; ++j) bf[j] = ld8(Bsh + (wn * 64 + j * 16 + c) * BK + g * 8);
    #pragma unroll
    for (int i = 0; i < 4; ++i)
      #pragma unroll
      for (int j = 0; j < 4; ++j)
        acc[i][j] = __builtin_amdgcn_mfma_f32_16x16x32_bf16(af[i], bf[j], acc[i][j], 0, 0, 0);
  }

  #pragma unroll
  for (int i = 0; i < 4; ++i)
    #pragma unroll
    for (int j = 0; j < 4; ++j)
      #pragma unroll
      for (int r = 0; r < 4; ++r) {
        const int row = rowBase + wm * 64 + i * 16 + g * 4 + r;
        const int col = colBase + wn * 64 + j * 16 + c;
        C[(size_t)row * D + col] = (TC)acc[i][j][r];
      }
}

__global__ __launch_bounds__(256) void qkv_gemm_bf16(
    const bf16_t* __restrict__ X,
    const bf16_t* __restrict__ Wq, const bf16_t* __restrict__ Wk,
    const bf16_t* __restrict__ Wv,
    bf16_t* __restrict__ Qo, bf16_t* __restrict__ Ko, bf16_t* __restrict__ Vo) {
  const bf16_t* W = (blockIdx.z == 0) ? Wq : (blockIdx.z == 1 ? Wk : Wv);
  bf16_t*       C = (blockIdx.z == 0) ? Qo : (blockIdx.z == 1 ? Ko : Vo);
  gemm_async<bf16_t>(X, W, C);
}

__global__ __launch_bounds__(256) void out_gemm_bf16(
    const bf16_t* __restrict__ A, const bf16_t* __restrict__ W,
    float* __restrict__ C) {
  gemm_async<float>(A, W, C);
}

// ---------------------------------------------------------------------------
// Fallback f32-operand GEMM (round-3 verified path, plain staging, stride 40)
// ---------------------------------------------------------------------------
template <typename TA, typename TW, typename TC>
__device__ __forceinline__ void gemm_body(const TA* __restrict__ A,
                                          const TW* __restrict__ W,
                                          TC* __restrict__ C) {
  constexpr int K  = D;
  constexpr int BK = 32;
  constexpr int LD = 40;
  __shared__ __align__(16) bf16_t Ash[128 * LD];
  __shared__ __align__(16) bf16_t Bsh[128 * LD];
  const int tid = threadIdx.x;
  const int w = tid >> 6, lane = tid & 63;
  const int c = lane & 15, g = lane >> 4;
  const int wm = w >> 1, wn = w & 1;
  const int rowBase = blockIdx.y * 128;
  const int colBase = blockIdx.x * 128;

  f32x4 acc[4][4] = {};

  for (int k0 = 0; k0 < K; k0 += BK) {
    __syncthreads();
    #pragma unroll
    for (int r = 0; r < 2; ++r) {
      const int cid = r * 256 + tid;
      const int row = cid >> 2, q = cid & 3;
      const bf16x8 av = ld8c(A + (size_t)(rowBase + row) * K + k0 + q * 8);
      const bf16x8 wv = ld8c(W + (size_t)(colBase + row) * K + k0 + q * 8);
      *(bf16x8*)(Ash + row * LD + q * 8) = av;
      *(bf16x8*)(Bsh + row * LD + q * 8) = wv;
    }
    __syncthreads();

    bf16x8 af[4], bf[4];
    #pragma unroll
    for (int i = 0; i < 4; ++i) af[i] = ld8(Ash + (wm * 64 + i * 16 + c) * LD + g * 8);
    #pragma unroll
    for (int j = 0; j < 4; ++j) bf[j] = ld8(Bsh + (wn * 64 + j * 16 + c) * LD + g * 8);
    #pragma unroll
    for (int i = 0; i < 4; ++i)
      #pragma unroll
      for (int j = 0; j < 4; ++j)
        acc[i][j] = __builtin_amdgcn_mfma_f32_16x16x32_bf16(af[i], bf[j], acc[i][j], 0, 0, 0);
  }

  #pragma unroll
  for (int i = 0; i < 4; ++i)
    #pragma unroll
    for (int j = 0; j < 4; ++j)
      #pragma unroll
      for (int r = 0; r < 4; ++r) {
        const int row = rowBase + wm * 64 + i * 16 + g * 4 + r;
        const int col = colBase + wn * 64 + j * 16 + c;
        C[(size_t)row * D + col] = (TC)acc[i][j][r];
      }
}

__global__ __launch_bounds__(256) void qkv_gemm_f32(
    const float* __restrict__ X,
    const float* __restrict__ Wq, const float* __restrict__ Wk,
    const float* __restrict__ Wv,
    bf16_t* __restrict__ Qo, bf16_t* __restrict__ Ko, bf16_t* __restrict__ Vo) {
  const float* W = (blockIdx.z == 0) ? Wq : (blockIdx.z == 1 ? Wk : Wv);
  bf16_t*      C = (blockIdx.z == 0) ? Qo : (blockIdx.z == 1 ? Ko : Vo);
  gemm_body<float, float, bf16_t>(X, W, C);
}

__global__ __launch_bounds__(256) void out_gemm_f32(
    const bf16_t* __restrict__ A, const float* __restrict__ W,
    float* __restrict__ C) {
  gemm_body<bf16_t, float, float>(A, W, C);
}

// ---------------------------------------------------------------------------
// Causal flash attention, pair-balanced. Block = q-tile pair {p, 63-p} x head,
// processed sequentially; every block does exactly 65 k-tile iters (causal).
// 256 threads = 4 waves, wave owns 16 q-rows. K-tile = 64 keys.
//   Ksh[d-chunk(4)][kn(64)][40]    B-frag for QK^T     (20 KB)
//   Vt [k-chunk(2)][d(128)][40]    B-frag for P*V      (20 KB)
//   Psh[wave(4)][k-chunk(2)][16][40]  A-frag for P*V   (10 KB)
// Q pre-scaled by sm*log2e -> softmax uses exp2.
// ---------------------------------------------------------------------------
__global__ __launch_bounds__(256) void attn_kernel(
    const bf16_t* __restrict__ Q, const bf16_t* __restrict__ Kb,
    const bf16_t* __restrict__ Vb, bf16_t* __restrict__ O,
    const int* __restrict__ causal_p) {
  constexpr int LDK = 40;
  __shared__ __align__(16) bf16_t Ksh[4 * 64 * LDK];
  __shared__ __align__(16) bf16_t Vt[2 * 128 * LDK];
  __shared__ __align__(16) bf16_t Psh[4 * 2 * 16 * LDK];

  const int p = blockIdx.x, h = blockIdx.y;
  const int tid = threadIdx.x, w = tid >> 6, lane = tid & 63;
  const int c = lane & 15, g = lane >> 4;
  const int causal = causal_p[0];
  constexpr float QS = 0.08838834764831845f * 1.4426950408889634f; // sm*log2e

  for (int tt = 0; tt < 2; ++tt) {
    const int t = (tt == 0) ? p : (63 - p);
    const int qbase = t * 64;
    const int wrow = qbase + w * 16;

    // Q fragments (A layout: m=lane&15, k=(lane>>4)*8+j), pre-scaled
    bf16x8 qf[4];
    #pragma unroll
    for (int kf = 0; kf < 4; ++kf) {
      const bf16x8 raw = ld8(Q + (size_t)(wrow + c) * D + h * DH + kf * 32 + g * 8);
      bf16x8 sc;
      #pragma unroll
      for (int e = 0; e < 8; ++e) sc[e] = (bf16_t)((float)raw[e] * QS);
      qf[kf] = sc;
    }

    f32x4 o_acc[8] = {};
    float m_st[4], l_st[4];
    #pragma unroll
    for (int r = 0; r < 4; ++r) { m_st[r] = -1e30f; l_st[r] = 0.f; }

    const int ktiles = causal ? (t + 1) : 64;

    for (int kt = 0; kt < ktiles; ++kt) {
      __syncthreads();  // prev iter's (or prev tile's) LDS reads done

      // --- stage K tile: 1024 8-elem chunks, 4/thread ---
      #pragma unroll
      for (int r = 0; r < 4; ++r) {
        const int cid = r * 256 + tid;
        const int kn = cid >> 4, d0 = (cid & 15) * 8;
        const bf16x8 kv = ld8(Kb + (size_t)(kt * 64 + kn) * D + h * DH + d0);
        *(bf16x8*)(Ksh + (d0 >> 5) * (64 * LDK) + kn * LDK + (d0 & 31)) = kv;
      }
      // --- stage V transposed: thread does 4(kn) x 8(d) sub-block ---
      {
        const int kn0 = (tid & 15) * 4, d0 = (tid >> 4) * 8;
        const int chunk = kn0 >> 5, knin = kn0 & 31;
        bf16x8 vv[4];
        #pragma unroll
        for (int rr = 0; rr < 4; ++rr)
          vv[rr] = ld8(Vb + (size_t)(kt * 64 + kn0 + rr) * D + h * DH + d0);
        #pragma unroll
        for (int jj = 0; jj < 8; ++jj) {
          bf16x4 tv;
          tv[0] = vv[0][jj]; tv[1] = vv[1][jj]; tv[2] = vv[2][jj]; tv[3] = vv[3][jj];
          *(bf16x4*)(Vt + chunk * (128 * LDK) + (d0 + jj) * LDK + knin) = tv;
        }
      }
      __syncthreads();

      // --- S = Q K^T : per wave 16x64 ---
      f32x4 s[4] = {};
      #pragma unroll
      for (int nf = 0; nf < 4; ++nf) {
        bf16x8 kk[4];
        #pragma unroll
        for (int kf = 0; kf < 4; ++kf)
          kk[kf] = ld8(Ksh + kf * (64 * LDK) + (nf * 16 + c) * LDK + g * 8);
        #pragma unroll
        for (int kf = 0; kf < 4; ++kf)
          s[nf] = __builtin_amdgcn_mfma_f32_16x16x32_bf16(qf[kf], kk[kf], s[nf], 0, 0, 0);
      }

      // --- causal mask (wave-uniform branch; only diagonal tile masks) ---
      if (causal && (kt * 64 + 63 > wrow)) {
        #pragma unroll
        for (int nf = 0; nf < 4; ++nf)
          #pragma unroll
          for (int r = 0; r < 4; ++r) {
            const int kc = kt * 64 + nf * 16 + c;
            const int qr = wrow + g * 4 + r;
            if (kc > qr) s[nf][r] = -1e30f;
          }
      }

      // --- online softmax (rows across 16-lane groups) + P -> LDS ---
      #pragma unroll
      for (int r = 0; r < 4; ++r) {
        float mx = fmaxf(fmaxf(s[0][r], s[1][r]), fmaxf(s[2][r], s[3][r]));
        #pragma unroll
        for (int d = 1; d < 16; d <<= 1) mx = fmaxf(mx, __shfl_xor(mx, d, 64));
        const float mnew = fmaxf(m_st[r], mx);
        const float alpha = exp2f(m_st[r] - mnew);
        m_st[r] = mnew;
        float rs = 0.f;
        const int qr = g * 4 + r;
        #pragma unroll
        for (int nf = 0; nf < 4; ++nf) {
          const float pv = exp2f(s[nf][r] - mnew);
          rs += pv;
          Psh[w * (2 * 16 * LDK) + (nf >> 1) * (16 * LDK) + qr * LDK + (nf & 1) * 16 + c] = (bf16_t)pv;
        }
        #pragma unroll
        for (int d = 1; d < 16; d <<= 1) rs += __shfl_xor(rs, d, 64);
        l_st[r] = l_st[r] * alpha + rs;
        #pragma unroll
        for (int nf = 0; nf < 8; ++nf) o_acc[nf][r] *= alpha;
      }

      // --- O += P V  (per-wave Psh; same-wave LDS ops are ordered) ---
      #pragma unroll
      for (int kf2 = 0; kf2 < 2; ++kf2) {
        const bf16x8 pf = ld8(Psh + w * (2 * 16 * LDK) + kf2 * (16 * LDK) + c * LDK + g * 8);
        #pragma unroll
        for (int nf = 0; nf < 8; ++nf) {
          const bf16x8 vf = ld8(Vt + kf2 * (128 * LDK) + (nf * 16 + c) * LDK + g * 8);
          o_acc[nf] = __builtin_amdgcn_mfma_f32_16x16x32_bf16(pf, vf, o_acc[nf], 0, 0, 0);
        }
      }
    }

    // --- normalize and write O ---
    #pragma unroll
    for (int r = 0; r < 4; ++r) {
      const float inv = 1.0f / l_st[r];
      const int row = wrow + g * 4 + r;
      #pragma unroll
      for (int nf = 0; nf < 8; ++nf)
        O[(size_t)row * D + h * DH + nf * 16 + c] = (bf16_t)(o_acc[nf][r] * inv);
    }
  }
}

// ---------------------------------------------------------------------------
extern "C" void kernel_launch(void* const* d_in, const int* in_sizes, int n_in,
                              void* d_out, int out_size, void* d_ws, size_t ws_size,
                              hipStream_t stream) {
  const float* x  = (const float*)d_in[0];
  const float* wq = (const float*)d_in[1];
  const float* wk = (const float*)d_in[2];
  const float* wv = (const float*)d_in[3];
  const float* wo = (const float*)d_in[4];
  const int* causal = (const int*)d_in[5];
  float* out = (float*)d_out;

  bf16_t* Qb = (bf16_t*)d_ws;
  bf16_t* Kb = Qb + (size_t)S * D;
  bf16_t* Vb = Kb + (size_t)S * D;
  bf16_t* Ob = Vb + (size_t)S * D;
  bf16_t* xb  = Ob + (size_t)S * D;
  bf16_t* wqb = xb + (size_t)S * D;
  bf16_t* wkb = wqb + (size_t)D * D;
  bf16_t* wvb = wkb + (size_t)D * D;
  bf16_t* wob = wvb + (size_t)D * D;

  const size_t need = (size_t)(4 * S * D + S * D + 4 * D * D) * sizeof(bf16_t);
  dim3 blk(256);

  if (ws_size >= need) {
    cvt_kernel<<<dim3(2048, 1, 6), blk, 0, stream>>>(x, wq, wk, wv, wo,
                                                     xb, wqb, wkb, wvb, wob);
    qkv_gemm_bf16<<<dim3(D / 128, S / 128, 3), blk, 0, stream>>>(xb, wqb, wkb, wvb, Qb, Kb, Vb);
    attn_kernel<<<dim3(32, H), blk, 0, stream>>>(Qb, Kb, Vb, Ob, causal);
    out_gemm_bf16<<<dim3(D / 128, S / 128), blk, 0, stream>>>(Ob, wob, out);
  } else {
    qkv_gemm_f32<<<dim3(D / 128, S / 128, 3), blk, 0, stream>>>(x, wq, wk, wv, Qb, Kb, Vb);
    attn_kernel<<<dim3(32, H), blk, 0, stream>>>(Qb, Kb, Vb, Ob, causal);
    out_gemm_f32<<<dim3(D / 128, S / 128), blk, 0, stream>>>(Ob, wo, out);
  }
}